// Round 2
// baseline (461.101 us; speedup 1.0000x reference)
//
#include <hip/hip_runtime.h>

// ---------------- problem constants ----------------
#define DD    128   // channel dim
#define LINE  256   // attention-axis length (H == W == 256)
#define NPOS  262144  // B*H*W = 4*256*256
#define BP    32    // positions per fused block (one (b,h) row segment)
#define TILE  64    // (fallback path) interior positions per block
#define NROW  66
#define NROWP 80
#define LSTR  136   // LDS row stride in bf16 elements (272 B, 16B-aligned rows)

typedef __bf16 bf16x8 __attribute__((ext_vector_type(8)));
typedef float  f32x4v __attribute__((ext_vector_type(4)));
typedef float  f32x2v __attribute__((ext_vector_type(2)));
typedef unsigned int u32x2v __attribute__((ext_vector_type(2)));
typedef unsigned int u32x4v __attribute__((ext_vector_type(4)));

static __device__ __forceinline__ unsigned short f2bf(float f) {
  union { float f; unsigned u; } v; v.f = f;
  unsigned u = v.u + 0x7FFFu + ((v.u >> 16) & 1u);   // RNE
  return (unsigned short)(u >> 16);
}
// packed f32->bf16 pair via native casts (compiler emits v_cvt_pk_bf16_f32)
static __device__ __forceinline__ unsigned pkbf(float a, float b) {
  __bf16 x = (__bf16)a, y = (__bf16)b;
  unsigned short ux = __builtin_bit_cast(unsigned short, x);
  unsigned short uy = __builtin_bit_cast(unsigned short, y);
  return (unsigned)ux | ((unsigned)uy << 16);
}
#define BF_LO(u) __uint_as_float((u) << 16)
#define BF_HI(u) __uint_as_float((u) & 0xffff0000u)

// =====================================================================
// PRIMARY PATH: make_mt + single fused kernel (projection in LDS)
// =====================================================================

// Mt[axis][d][c] = sum_e Wq[e][c] * Wk[e][d] / sqrt(D)
// (B-fragment layout for XM = X @ M: row = output col d, contiguous = k = c)
__global__ void make_mt_kernel(const float* __restrict__ Wq_h, const float* __restrict__ Wk_h,
                               const float* __restrict__ Wq_w, const float* __restrict__ Wk_w,
                               unsigned short* __restrict__ Ms) {
  const float* Wq = blockIdx.y ? Wq_w : Wq_h;
  const float* Wk = blockIdx.y ? Wk_w : Wk_h;
  unsigned short* M = Ms + blockIdx.y * (DD * DD);
  int d = blockIdx.x, c = threadIdx.x;
  float acc = 0.f;
  for (int e = 0; e < DD; ++e) acc += Wq[e * DD + c] * Wk[e * DD + d];  // Wk uniform -> scalar
  M[d * DD + c] = f2bf(acc * 0.08838834764831845f);  // 1/sqrt(128)
}

static __device__ __forceinline__ float dot8(const float q[8], f32x4v a, f32x4v b) {
  return q[0] * a.x + q[1] * a.y + q[2] * a.z + q[3] * a.w
       + q[4] * b.x + q[5] * b.y + q[6] * b.z + q[7] * b.w;
}
static __device__ __forceinline__ float red16(float v) {
#pragma unroll
  for (int m = 1; m < 16; m <<= 1) v += __shfl_xor(v, m, 16);
  return v;
}
static __device__ __forceinline__ void dec4(unsigned lo, unsigned hi, float* q) {
  q[0] = BF_LO(lo); q[1] = BF_HI(lo); q[2] = BF_LO(hi); q[3] = BF_HI(hi);
}

// Fused: per-block XM projection (MFMA, A-frags direct from global, XM in LDS)
// + both-axes band attention. Block = 32 consecutive w-positions at fixed (b,h).
// One barrier total; LDS = 17.4 KB -> 8 blocks/CU.
__global__ __launch_bounds__(256, 8) void fused_kernel(const float* __restrict__ x,
                                                       const float* __restrict__ kv,
                                                       const unsigned short* __restrict__ Mt,
                                                       float* __restrict__ out) {
  __shared__ unsigned short xm_s[2 * BP * LSTR];   // 17408 B (XMh | XMw, bf16)

  const int tid = threadIdx.x;
  const int y  = blockIdx.y;               // b*256 + h
  const int h  = y & 255;
  const int w0 = blockIdx.x * BP;
  const long row0 = (long)y * 256 + w0;    // first global position of this block

  // ---- Phase 1: XM = x_tile @ Mt for both matrices; A-frags from global ----
  {
    const int wave = tid >> 6, lane = tid & 63;
    const int r16 = lane & 15, q = lane >> 4;
    const unsigned short* Mm = Mt + (wave >> 1) * (DD * DD);   // wave>>1: h or w matrix
    unsigned short* XO = xm_s + (wave >> 1) * (BP * LSTR);
#pragma unroll
    for (int rt = 0; rt < BP / 16; ++rt) {
      bf16x8 a[4];
#pragma unroll
      for (int ks = 0; ks < 4; ++ks) {
        const float* xp = x + (row0 + rt * 16 + r16) * DD + ks * 32 + q * 8;
        f32x4v v0 = *(const f32x4v*)xp;
        f32x4v v1 = *(const f32x4v*)(xp + 4);
        u32x4v pk;
        pk.x = pkbf(v0.x, v0.y); pk.y = pkbf(v0.z, v0.w);
        pk.z = pkbf(v1.x, v1.y); pk.w = pkbf(v1.z, v1.w);
        a[ks] = __builtin_bit_cast(bf16x8, pk);
      }
#pragma unroll
      for (int ci = 0; ci < 4; ++ci) {
        int ct = (wave & 1) * 4 + ci;                          // column tile 0..7
        f32x4v acc = {0.f, 0.f, 0.f, 0.f};
#pragma unroll
        for (int ks = 0; ks < 4; ++ks) {
          bf16x8 b = __builtin_bit_cast(
              bf16x8, *(const u32x4v*)(Mm + (ct * 16 + r16) * DD + ks * 32 + q * 8));
          acc = __builtin_amdgcn_mfma_f32_16x16x32_bf16(a[ks], b, acc, 0, 0, 0);
        }
#pragma unroll
        for (int r = 0; r < 4; ++r) {
          int row = rt * 16 + q * 4 + r;   // C/D: col=lane&15, row=quad*4+reg
          XO[row * LSTR + ct * 16 + r16] = f2bf(acc[r]);
        }
      }
    }
  }
  __syncthreads();

  // ---- Phase 2: band attention, 16 lanes per position, qh/qw from LDS ----
  for (int it = 0; it < BP / 16; ++it) {
    const int g = it * 16 + (tid >> 4), l = tid & 15;
    const int w = w0 + g;
    const long pos = row0 + g;
    const long pn = (h > 0)   ? pos - 256 : pos;
    const long ps = (h < 255) ? pos + 256 : pos;
    const long pw = (w > 0)   ? pos - 1   : pos;
    const long pe = (w < 255) ? pos + 1   : pos;
    const int c0 = l * 4, c1 = 64 + l * 4;
    const float* kc = kv + pos * DD;
    const float* kn = kv + pn * DD;
    const float* ksr = kv + ps * DD;
    const float* kw = kv + pw * DD;
    const float* ke = kv + pe * DD;

    u32x2v xh0 = *(const u32x2v*)&xm_s[g * LSTR + c0];
    u32x2v xh1 = *(const u32x2v*)&xm_s[g * LSTR + c1];
    u32x2v xw0 = *(const u32x2v*)&xm_s[BP * LSTR + g * LSTR + c0];
    u32x2v xw1 = *(const u32x2v*)&xm_s[BP * LSTR + g * LSTR + c1];
    float qh[8], qw[8];
    dec4(xh0.x, xh0.y, qh); dec4(xh1.x, xh1.y, qh + 4);
    dec4(xw0.x, xw0.y, qw); dec4(xw1.x, xw1.y, qw + 4);

    // score pass: vectors are consumed into dots, not kept live
    float sh_n, sh_c, sh_s, sw_w, sw_c, sw_e;
    {
      f32x4v a, b;
      a = *(const f32x4v*)(kn + c0);  b = *(const f32x4v*)(kn + c1);
      sh_n = dot8(qh, a, b);
      a = *(const f32x4v*)(kc + c0);  b = *(const f32x4v*)(kc + c1);
      sh_c = dot8(qh, a, b); sw_c = dot8(qw, a, b);
      a = *(const f32x4v*)(ksr + c0); b = *(const f32x4v*)(ksr + c1);
      sh_s = dot8(qh, a, b);
      a = *(const f32x4v*)(kw + c0);  b = *(const f32x4v*)(kw + c1);
      sw_w = dot8(qw, a, b);
      a = *(const f32x4v*)(ke + c0);  b = *(const f32x4v*)(ke + c1);
      sw_e = dot8(qw, a, b);
    }
    sh_n = red16(sh_n); sh_c = red16(sh_c); sh_s = red16(sh_s);
    sw_w = red16(sw_w); sw_c = red16(sw_c); sw_e = red16(sw_e);

    if (h == 0)   sh_n = -1e30f;
    if (h == 255) sh_s = -1e30f;
    if (w == 0)   sw_w = -1e30f;
    if (w == 255) sw_e = -1e30f;

    float mh = fmaxf(sh_n, fmaxf(sh_c, sh_s));
    float e0 = __expf(sh_n - mh), e1 = __expf(sh_c - mh), e2 = __expf(sh_s - mh);
    float ih = 1.f / (e0 + e1 + e2);
    float ph0 = e0 * ih, ph1 = e1 * ih, ph2 = e2 * ih;

    float mw = fmaxf(sw_w, fmaxf(sw_c, sw_e));
    float f0 = __expf(sw_w - mw), f1 = __expf(sw_c - mw), f2 = __expf(sw_e - mw);
    float iw = 1.f / (f0 + f1 + f2);
    float pw0 = f0 * iw, pw1 = f1 * iw, pw2 = f2 * iw;
    float pc = ph1 + pw1;

    // output pass: re-load rows (L1/L2-hot), accumulate incrementally
    f32x4v oA, oB;
    {
      f32x4v a, b;
      a = *(const f32x4v*)(kc + c0);  b = *(const f32x4v*)(kc + c1);
      oA.x = pc * a.x; oA.y = pc * a.y; oA.z = pc * a.z; oA.w = pc * a.w;
      oB.x = pc * b.x; oB.y = pc * b.y; oB.z = pc * b.z; oB.w = pc * b.w;
      a = *(const f32x4v*)(kn + c0);  b = *(const f32x4v*)(kn + c1);
      oA.x += ph0 * a.x; oA.y += ph0 * a.y; oA.z += ph0 * a.z; oA.w += ph0 * a.w;
      oB.x += ph0 * b.x; oB.y += ph0 * b.y; oB.z += ph0 * b.z; oB.w += ph0 * b.w;
      a = *(const f32x4v*)(ksr + c0); b = *(const f32x4v*)(ksr + c1);
      oA.x += ph2 * a.x; oA.y += ph2 * a.y; oA.z += ph2 * a.z; oA.w += ph2 * a.w;
      oB.x += ph2 * b.x; oB.y += ph2 * b.y; oB.z += ph2 * b.z; oB.w += ph2 * b.w;
      a = *(const f32x4v*)(kw + c0);  b = *(const f32x4v*)(kw + c1);
      oA.x += pw0 * a.x; oA.y += pw0 * a.y; oA.z += pw0 * a.z; oA.w += pw0 * a.w;
      oB.x += pw0 * b.x; oB.y += pw0 * b.y; oB.z += pw0 * b.z; oB.w += pw0 * b.w;
      a = *(const f32x4v*)(ke + c0);  b = *(const f32x4v*)(ke + c1);
      oA.x += pw2 * a.x; oA.y += pw2 * a.y; oA.z += pw2 * a.z; oA.w += pw2 * a.w;
      oB.x += pw2 * b.x; oB.y += pw2 * b.y; oB.z += pw2 * b.z; oB.w += pw2 * b.w;
    }
    *(f32x4v*)(out + pos * DD + c0) = oA;
    *(f32x4v*)(out + pos * DD + c1) = oB;
  }
}

// =====================================================================
// FALLBACK PATH (Round-1, validated) — used only if ws_size is too small
// =====================================================================
__global__ void make_m_kernel(const float* __restrict__ Wq_h, const float* __restrict__ Wk_h,
                              const float* __restrict__ Wq_w, const float* __restrict__ Wk_w,
                              unsigned short* __restrict__ Ms) {
  const float* Wq = blockIdx.y ? Wq_w : Wq_h;
  const float* Wk = blockIdx.y ? Wk_w : Wk_h;
  unsigned short* M = Ms + blockIdx.y * (DD * DD);
  int d = blockIdx.x, c = threadIdx.x;
  float acc = 0.f;
  for (int e = 0; e < DD; ++e) acc += Wq[e * DD + d] * Wk[e * DD + c];
  M[d * DD + c] = f2bf(acc * 0.08838834764831845f);
}

template <int AXIS, bool ADD>
__global__ __launch_bounds__(256) void axial_pass(const float* __restrict__ x,
                                                  const float* __restrict__ kv,
                                                  const unsigned short* __restrict__ M,
                                                  float* __restrict__ out) {
  __shared__ unsigned short kv_s[NROWP * LSTR];
  __shared__ unsigned short x_s[TILE * LSTR];
  __shared__ unsigned short kvm_s[NROW * LSTR];
  __shared__ float s_s[3 * TILE];
  __shared__ float p_s[3 * TILE];

  const int tid  = threadIdx.x;
  const int seg0 = blockIdx.x * TILE;
  const int line = blockIdx.y;

  size_t base; int stride;
  if (AXIS == 0) {
    int b = line >> 8, w = line & 255;
    base = (size_t)b * (256 * 256 * 128) + (size_t)w * DD;
    stride = 256 * 128;
  } else {
    base = (size_t)line * (256 * 128);
    stride = DD;
  }

  for (int u = tid; u < NROWP * 32; u += 256) {
    int row = u >> 5, c4 = u & 31;
    u32x2v wv; wv.x = 0u; wv.y = 0u;
    if (row < NROW) {
      int pos = seg0 - 1 + row;
      pos = pos < 0 ? 0 : (pos > LINE - 1 ? LINE - 1 : pos);
      f32x4v v = *(const f32x4v*)(kv + base + (size_t)pos * stride + c4 * 4);
      wv.x = (unsigned)f2bf(v.x) | ((unsigned)f2bf(v.y) << 16);
      wv.y = (unsigned)f2bf(v.z) | ((unsigned)f2bf(v.w) << 16);
    }
    *(u32x2v*)&kv_s[row * LSTR + c4 * 4] = wv;
  }
  for (int u = tid; u < TILE * 32; u += 256) {
    int row = u >> 5, c4 = u & 31;
    f32x4v v = *(const f32x4v*)(x + base + (size_t)(seg0 + row) * stride + c4 * 4);
    u32x2v wv;
    wv.x = (unsigned)f2bf(v.x) | ((unsigned)f2bf(v.y) << 16);
    wv.y = (unsigned)f2bf(v.z) | ((unsigned)f2bf(v.w) << 16);
    *(u32x2v*)&x_s[row * LSTR + c4 * 4] = wv;
  }
  __syncthreads();

  {
    const int wave = tid >> 6, lane = tid & 63;
    const int r16 = lane & 15, q = lane >> 4;
    for (int ct = wave * 2; ct < wave * 2 + 2; ++ct) {
      bf16x8 b[4];
#pragma unroll
      for (int ks = 0; ks < 4; ++ks)
        b[ks] = __builtin_bit_cast(
            bf16x8, *(const u32x4v*)(M + (ct * 16 + r16) * DD + ks * 32 + q * 8));
#pragma unroll
      for (int rt = 0; rt < 5; ++rt) {
        f32x4v acc = {0.f, 0.f, 0.f, 0.f};
#pragma unroll
        for (int ks = 0; ks < 4; ++ks) {
          bf16x8 a = __builtin_bit_cast(
              bf16x8, *(const u32x4v*)&kv_s[(rt * 16 + r16) * LSTR + ks * 32 + q * 8]);
          acc = __builtin_amdgcn_mfma_f32_16x16x32_bf16(a, b[ks], acc, 0, 0, 0);
        }
        int col = ct * 16 + r16;
#pragma unroll
        for (int r = 0; r < 4; ++r) {
          int row = rt * 16 + q * 4 + r;
          if (row < NROW) kvm_s[row * LSTR + col] = f2bf(acc[r]);
        }
      }
    }
  }
  __syncthreads();

  {
    int i = tid >> 2, sub = tid & 3;
    float s0 = 0.f, s1 = 0.f, s2 = 0.f;
#pragma unroll
    for (int ch = 0; ch < 4; ++ch) {
      int off = sub * 32 + ch * 8;
      float xf[8];
      {
        u32x4v t = *(const u32x4v*)&x_s[i * LSTR + off];
        xf[0] = BF_LO(t.x); xf[1] = BF_HI(t.x); xf[2] = BF_LO(t.y); xf[3] = BF_HI(t.y);
        xf[4] = BF_LO(t.z); xf[5] = BF_HI(t.z); xf[6] = BF_LO(t.w); xf[7] = BF_HI(t.w);
      }
      {
        u32x4v t = *(const u32x4v*)&kvm_s[(i + 0) * LSTR + off];
        s0 += xf[0]*BF_LO(t.x) + xf[1]*BF_HI(t.x) + xf[2]*BF_LO(t.y) + xf[3]*BF_HI(t.y)
            + xf[4]*BF_LO(t.z) + xf[5]*BF_HI(t.z) + xf[6]*BF_LO(t.w) + xf[7]*BF_HI(t.w);
      }
      {
        u32x4v t = *(const u32x4v*)&kvm_s[(i + 1) * LSTR + off];
        s1 += xf[0]*BF_LO(t.x) + xf[1]*BF_HI(t.x) + xf[2]*BF_LO(t.y) + xf[3]*BF_HI(t.y)
            + xf[4]*BF_LO(t.z) + xf[5]*BF_HI(t.z) + xf[6]*BF_LO(t.w) + xf[7]*BF_HI(t.w);
      }
      {
        u32x4v t = *(const u32x4v*)&kvm_s[(i + 2) * LSTR + off];
        s2 += xf[0]*BF_LO(t.x) + xf[1]*BF_HI(t.x) + xf[2]*BF_LO(t.y) + xf[3]*BF_HI(t.y)
            + xf[4]*BF_LO(t.z) + xf[5]*BF_HI(t.z) + xf[6]*BF_LO(t.w) + xf[7]*BF_HI(t.w);
      }
    }
    s0 += __shfl_xor(s0, 1); s0 += __shfl_xor(s0, 2);
    s1 += __shfl_xor(s1, 1); s1 += __shfl_xor(s1, 2);
    s2 += __shfl_xor(s2, 1); s2 += __shfl_xor(s2, 2);
    if (sub == 0) {
      int gp = seg0 + i;
      s_s[0 * TILE + i] = (gp - 1 >= 0)   ? s0 : -1e30f;
      s_s[1 * TILE + i] = s1;
      s_s[2 * TILE + i] = (gp + 1 < LINE) ? s2 : -1e30f;
    }
  }
  __syncthreads();

  if (tid < TILE) {
    float s0 = s_s[0 * TILE + tid], s1 = s_s[1 * TILE + tid], s2 = s_s[2 * TILE + tid];
    float m = fmaxf(s0, fmaxf(s1, s2));
    float e0 = __expf(s0 - m), e1 = __expf(s1 - m), e2 = __expf(s2 - m);
    float inv = 1.f / (e0 + e1 + e2);
    p_s[0 * TILE + tid] = e0 * inv;
    p_s[1 * TILE + tid] = e1 * inv;
    p_s[2 * TILE + tid] = e2 * inv;
  }
  __syncthreads();

  for (int r = 0; r < 16; ++r) {
    int u  = r * 256 + tid;
    int i  = u >> 6, dp = u & 63;
    float p0 = p_s[0 * TILE + i], p1 = p_s[1 * TILE + i], p2 = p_s[2 * TILE + i];
    unsigned a0 = *(const unsigned*)&kv_s[(i + 0) * LSTR + dp * 2];
    unsigned a1 = *(const unsigned*)&kv_s[(i + 1) * LSTR + dp * 2];
    unsigned a2 = *(const unsigned*)&kv_s[(i + 2) * LSTR + dp * 2];
    f32x2v o;
    o.x = p0 * BF_LO(a0) + p1 * BF_LO(a1) + p2 * BF_LO(a2);
    o.y = p0 * BF_HI(a0) + p1 * BF_HI(a1) + p2 * BF_HI(a2);
    size_t oidx = base + (size_t)(seg0 + i) * stride + dp * 2;
    if (ADD) {
      f32x2v prev = *(const f32x2v*)(out + oidx);
      o.x += prev.x; o.y += prev.y;
    }
    *(f32x2v*)(out + oidx) = o;
  }
}

// =====================================================================
extern "C" void kernel_launch(void* const* d_in, const int* in_sizes, int n_in,
                              void* d_out, int out_size, void* d_ws, size_t ws_size,
                              hipStream_t stream) {
  const float* x    = (const float*)d_in[0];
  const float* kv   = (const float*)d_in[1];
  const float* Wq_h = (const float*)d_in[2];
  const float* Wk_h = (const float*)d_in[3];
  const float* Wq_w = (const float*)d_in[4];
  const float* Wk_w = (const float*)d_in[5];
  float* out = (float*)d_out;

  const size_t ms_bytes = 2ull * DD * DD * 2;  // 65536

  if (ws_size >= ms_bytes) {
    unsigned short* Ms = (unsigned short*)d_ws;
    make_mt_kernel<<<dim3(DD, 2), dim3(DD), 0, stream>>>(Wq_h, Wk_h, Wq_w, Wk_w, Ms);
    fused_kernel<<<dim3(LINE / BP, 4 * LINE), dim3(256), 0, stream>>>(x, kv, Ms, out);
  } else {
    unsigned short* Ms = (unsigned short*)d_ws;  // 64 KB
    make_m_kernel<<<dim3(DD, 2), dim3(DD), 0, stream>>>(Wq_h, Wk_h, Wq_w, Wk_w, Ms);
    dim3 grid(LINE / TILE, 4 * 256);
    axial_pass<0, false><<<grid, dim3(256), 0, stream>>>(x, kv, Ms, out);
    axial_pass<1, true ><<<grid, dim3(256), 0, stream>>>(x, kv, Ms + DD * DD, out);
  }
}

// Round 3
// 459.093 us; speedup vs baseline: 1.0044x; 1.0044x over previous
//
#include <hip/hip_runtime.h>

// ---------------- problem constants ----------------
#define DD    128   // channel dim
#define LINE  256   // attention-axis length (H == W == 256)
#define NPOS  262144  // B*H*W = 4*256*256
#define BP    32    // positions per fused block (one (b,h) row segment)
#define TILE  64    // (fallback path) interior positions per block
#define NROW  66
#define NROWP 80
#define LSTR  136   // (fallback path) LDS row stride in bf16 elements

typedef __bf16 bf16x8 __attribute__((ext_vector_type(8)));
typedef float  f32x4v __attribute__((ext_vector_type(4)));
typedef float  f32x2v __attribute__((ext_vector_type(2)));
typedef unsigned int u32x2v __attribute__((ext_vector_type(2)));
typedef unsigned int u32x4v __attribute__((ext_vector_type(4)));

static __device__ __forceinline__ unsigned short f2bf(float f) {
  union { float f; unsigned u; } v; v.f = f;
  unsigned u = v.u + 0x7FFFu + ((v.u >> 16) & 1u);   // RNE
  return (unsigned short)(u >> 16);
}
// packed f32->bf16 pair via native casts (compiler emits v_cvt_pk_bf16_f32)
static __device__ __forceinline__ unsigned pkbf(float a, float b) {
  __bf16 x = (__bf16)a, y = (__bf16)b;
  unsigned short ux = __builtin_bit_cast(unsigned short, x);
  unsigned short uy = __builtin_bit_cast(unsigned short, y);
  return (unsigned)ux | ((unsigned)uy << 16);
}
#define BF_LO(u) __uint_as_float((u) << 16)
#define BF_HI(u) __uint_as_float((u) & 0xffff0000u)

// =====================================================================
// PRIMARY PATH: make_mt + single fused kernel (projection + kv in LDS)
// =====================================================================

// Mt[axis][d][c] = sum_e Wq[e][c] * Wk[e][d] / sqrt(D)
// (B-fragment layout for XM = X @ M: row = output col d, contiguous = k = c)
__global__ void make_mt_kernel(const float* __restrict__ Wq_h, const float* __restrict__ Wk_h,
                               const float* __restrict__ Wq_w, const float* __restrict__ Wk_w,
                               unsigned short* __restrict__ Ms) {
  const float* Wq = blockIdx.y ? Wq_w : Wq_h;
  const float* Wk = blockIdx.y ? Wk_w : Wk_h;
  unsigned short* M = Ms + blockIdx.y * (DD * DD);
  int d = blockIdx.x, c = threadIdx.x;
  float acc = 0.f;
  for (int e = 0; e < DD; ++e) acc += Wq[e * DD + c] * Wk[e * DD + d];  // Wk uniform -> scalar
  M[d * DD + c] = f2bf(acc * 0.08838834764831845f);  // 1/sqrt(128)
}

static __device__ __forceinline__ float red16(float v) {
#pragma unroll
  for (int m = 1; m < 16; m <<= 1) v += __shfl_xor(v, m, 16);
  return v;
}
static __device__ __forceinline__ void dec4(unsigned lo, unsigned hi, float* q) {
  q[0] = BF_LO(lo); q[1] = BF_HI(lo); q[2] = BF_LO(hi); q[3] = BF_HI(hi);
}
// decode 8 channels (co0..co0+3, co0+64..co0+67) from a bf16 LDS row
static __device__ __forceinline__ void ld8(const unsigned short* base, int co0, float* f) {
  u32x2v t0 = *(const u32x2v*)(base + co0);
  u32x2v t1 = *(const u32x2v*)(base + co0 + 64);
  dec4(t0.x, t0.y, f); dec4(t1.x, t1.y, f + 4);
}

// Fused: kv band staged in LDS (bf16) + XM projection (MFMA, A-frags direct
// from global, XM in LDS) + both-axes band attention from LDS.
// Block = 32 consecutive w-positions at fixed (b,h). LDS 40960 B -> 4 blocks/CU.
__global__ __launch_bounds__(256, 4) void fused_kernel(const float* __restrict__ x,
                                                       const float* __restrict__ kv,
                                                       const unsigned short* __restrict__ Mt,
                                                       float* __restrict__ out) {
  __shared__ unsigned short xm_s[2 * BP * DD];   // 16384 B (XMh | XMw, stride 128)
  __shared__ unsigned short kv_s[96 * DD];       // 24576 B (n[32] | c[32] | s[32], bf16)

  const int tid = threadIdx.x;
  const int y  = blockIdx.y;               // b*256 + h
  const int h  = y & 255;
  const int b  = y >> 8;
  const int w0 = blockIdx.x * BP;
  const long row0 = (long)y * 256 + w0;    // first global position of this block

  // ---- Phase 0: stage kv n/c/s bands -> bf16 LDS (12 independent loads/thread)
  for (int u = tid; u < 96 * 32; u += 256) {
    int r = u >> 5, c4 = u & 31;
    int hh = h + (r >> 5) - 1;             // region 0=n,1=c,2=s
    hh = hh < 0 ? 0 : (hh > 255 ? 255 : hh);
    long p = ((long)(b * 256 + hh) * 256 + (w0 + (r & 31))) * DD + c4 * 4;
    f32x4v v = *(const f32x4v*)(kv + p);
    u32x2v pk2; pk2.x = pkbf(v.x, v.y); pk2.y = pkbf(v.z, v.w);
    *(u32x2v*)&kv_s[r * DD + c4 * 4] = pk2;
  }

  // ---- Phase 1: XM = x_tile @ Mt for both matrices; A-frags from global ----
  {
    const int wave = tid >> 6, lane = tid & 63;
    const int r16 = lane & 15, q = lane >> 4;
    const unsigned short* Mm = Mt + (wave >> 1) * (DD * DD);   // wave>>1: h or w matrix
    unsigned short* XO = xm_s + (wave >> 1) * (BP * DD);
#pragma unroll
    for (int rt = 0; rt < BP / 16; ++rt) {
      bf16x8 a[4];
#pragma unroll
      for (int ks = 0; ks < 4; ++ks) {
        const float* xp = x + (row0 + rt * 16 + r16) * DD + ks * 32 + q * 8;
        f32x4v v0 = *(const f32x4v*)xp;
        f32x4v v1 = *(const f32x4v*)(xp + 4);
        u32x4v pk;
        pk.x = pkbf(v0.x, v0.y); pk.y = pkbf(v0.z, v0.w);
        pk.z = pkbf(v1.x, v1.y); pk.w = pkbf(v1.z, v1.w);
        a[ks] = __builtin_bit_cast(bf16x8, pk);
      }
#pragma unroll
      for (int ci = 0; ci < 4; ++ci) {
        int ct = (wave & 1) * 4 + ci;                          // column tile 0..7
        f32x4v acc = {0.f, 0.f, 0.f, 0.f};
#pragma unroll
        for (int ks = 0; ks < 4; ++ks) {
          bf16x8 bb = __builtin_bit_cast(
              bf16x8, *(const u32x4v*)(Mm + (ct * 16 + r16) * DD + ks * 32 + q * 8));
          acc = __builtin_amdgcn_mfma_f32_16x16x32_bf16(a[ks], bb, acc, 0, 0, 0);
        }
#pragma unroll
        for (int r = 0; r < 4; ++r) {
          int row = rt * 16 + q * 4 + r;   // C/D: col=lane&15, row=quad*4+reg
          XO[row * DD + ct * 16 + r16] = f2bf(acc[r]);
        }
      }
    }
  }
  __syncthreads();

  // ---- Phase 2: band attention, all operands from LDS ----
  for (int it = 0; it < BP / 16; ++it) {
    const int g = it * 16 + (tid >> 4), l = tid & 15;
    const int w = w0 + g;
    const long pos = row0 + g;
    const int co0 = l * 4;

    // edge rows from global (only groups 0 / 31; latency hidden by other groups)
    float wv[8], ev[8];
    if (g == 0) {
      const long pwp = (w > 0) ? pos - 1 : pos;
      f32x4v a0 = *(const f32x4v*)(kv + pwp * DD + co0);
      f32x4v a1 = *(const f32x4v*)(kv + pwp * DD + co0 + 64);
      wv[0]=a0.x; wv[1]=a0.y; wv[2]=a0.z; wv[3]=a0.w;
      wv[4]=a1.x; wv[5]=a1.y; wv[6]=a1.z; wv[7]=a1.w;
    } else {
      ld8(&kv_s[(31 + g) * DD], co0, wv);      // c-region row g-1
    }
    if (g == 31) {
      const long pep = (w < 255) ? pos + 1 : pos;
      f32x4v a0 = *(const f32x4v*)(kv + pep * DD + co0);
      f32x4v a1 = *(const f32x4v*)(kv + pep * DD + co0 + 64);
      ev[0]=a0.x; ev[1]=a0.y; ev[2]=a0.z; ev[3]=a0.w;
      ev[4]=a1.x; ev[5]=a1.y; ev[6]=a1.z; ev[7]=a1.w;
    } else {
      ld8(&kv_s[(33 + g) * DD], co0, ev);      // c-region row g+1
    }

    float nv[8], cv[8], sv[8];
    ld8(&kv_s[g * DD],        co0, nv);        // n-region
    ld8(&kv_s[(32 + g) * DD], co0, cv);        // c-region
    ld8(&kv_s[(64 + g) * DD], co0, sv);        // s-region

    float qh[8], qw[8];
    ld8(&xm_s[g * DD],            co0, qh);
    ld8(&xm_s[(BP + g) * DD],     co0, qw);

    float sh_n = 0.f, sh_c = 0.f, sh_s = 0.f, sw_w = 0.f, sw_c = 0.f, sw_e = 0.f;
#pragma unroll
    for (int k = 0; k < 8; ++k) {
      sh_n += qh[k] * nv[k]; sh_c += qh[k] * cv[k]; sh_s += qh[k] * sv[k];
      sw_w += qw[k] * wv[k]; sw_c += qw[k] * cv[k]; sw_e += qw[k] * ev[k];
    }
    sh_n = red16(sh_n); sh_c = red16(sh_c); sh_s = red16(sh_s);
    sw_w = red16(sw_w); sw_c = red16(sw_c); sw_e = red16(sw_e);

    if (h == 0)   sh_n = -1e30f;
    if (h == 255) sh_s = -1e30f;
    if (w == 0)   sw_w = -1e30f;
    if (w == 255) sw_e = -1e30f;

    float mh = fmaxf(sh_n, fmaxf(sh_c, sh_s));
    float e0 = __expf(sh_n - mh), e1 = __expf(sh_c - mh), e2 = __expf(sh_s - mh);
    float ih = 1.f / (e0 + e1 + e2);
    float ph0 = e0 * ih, ph1 = e1 * ih, ph2 = e2 * ih;

    float mw = fmaxf(sw_w, fmaxf(sw_c, sw_e));
    float f0 = __expf(sw_w - mw), f1 = __expf(sw_c - mw), f2 = __expf(sw_e - mw);
    float iw = 1.f / (f0 + f1 + f2);
    float pw0 = f0 * iw, pw1 = f1 * iw, pw2 = f2 * iw;
    float pc = ph1 + pw1;

    f32x4v oA, oB;
#pragma unroll
    for (int j = 0; j < 4; ++j) {
      oA[j] = ph0 * nv[j]     + pc * cv[j]     + ph2 * sv[j]     + pw0 * wv[j]     + pw2 * ev[j];
      oB[j] = ph0 * nv[4 + j] + pc * cv[4 + j] + ph2 * sv[4 + j] + pw0 * wv[4 + j] + pw2 * ev[4 + j];
    }
    *(f32x4v*)(out + pos * DD + co0) = oA;
    *(f32x4v*)(out + pos * DD + co0 + 64) = oB;
  }
}

// =====================================================================
// FALLBACK PATH (Round-1, validated) — used only if ws_size is too small
// =====================================================================
__global__ void make_m_kernel(const float* __restrict__ Wq_h, const float* __restrict__ Wk_h,
                              const float* __restrict__ Wq_w, const float* __restrict__ Wk_w,
                              unsigned short* __restrict__ Ms) {
  const float* Wq = blockIdx.y ? Wq_w : Wq_h;
  const float* Wk = blockIdx.y ? Wk_w : Wk_h;
  unsigned short* M = Ms + blockIdx.y * (DD * DD);
  int d = blockIdx.x, c = threadIdx.x;
  float acc = 0.f;
  for (int e = 0; e < DD; ++e) acc += Wq[e * DD + d] * Wk[e * DD + c];
  M[d * DD + c] = f2bf(acc * 0.08838834764831845f);
}

template <int AXIS, bool ADD>
__global__ __launch_bounds__(256) void axial_pass(const float* __restrict__ x,
                                                  const float* __restrict__ kv,
                                                  const unsigned short* __restrict__ M,
                                                  float* __restrict__ out) {
  __shared__ unsigned short kv_s[NROWP * LSTR];
  __shared__ unsigned short x_s[TILE * LSTR];
  __shared__ unsigned short kvm_s[NROW * LSTR];
  __shared__ float s_s[3 * TILE];
  __shared__ float p_s[3 * TILE];

  const int tid  = threadIdx.x;
  const int seg0 = blockIdx.x * TILE;
  const int line = blockIdx.y;

  size_t base; int stride;
  if (AXIS == 0) {
    int b = line >> 8, w = line & 255;
    base = (size_t)b * (256 * 256 * 128) + (size_t)w * DD;
    stride = 256 * 128;
  } else {
    base = (size_t)line * (256 * 128);
    stride = DD;
  }

  for (int u = tid; u < NROWP * 32; u += 256) {
    int row = u >> 5, c4 = u & 31;
    u32x2v wv; wv.x = 0u; wv.y = 0u;
    if (row < NROW) {
      int pos = seg0 - 1 + row;
      pos = pos < 0 ? 0 : (pos > LINE - 1 ? LINE - 1 : pos);
      f32x4v v = *(const f32x4v*)(kv + base + (size_t)pos * stride + c4 * 4);
      wv.x = (unsigned)f2bf(v.x) | ((unsigned)f2bf(v.y) << 16);
      wv.y = (unsigned)f2bf(v.z) | ((unsigned)f2bf(v.w) << 16);
    }
    *(u32x2v*)&kv_s[row * LSTR + c4 * 4] = wv;
  }
  for (int u = tid; u < TILE * 32; u += 256) {
    int row = u >> 5, c4 = u & 31;
    f32x4v v = *(const f32x4v*)(x + base + (size_t)(seg0 + row) * stride + c4 * 4);
    u32x2v wv;
    wv.x = (unsigned)f2bf(v.x) | ((unsigned)f2bf(v.y) << 16);
    wv.y = (unsigned)f2bf(v.z) | ((unsigned)f2bf(v.w) << 16);
    *(u32x2v*)&x_s[row * LSTR + c4 * 4] = wv;
  }
  __syncthreads();

  {
    const int wave = tid >> 6, lane = tid & 63;
    const int r16 = lane & 15, q = lane >> 4;
    for (int ct = wave * 2; ct < wave * 2 + 2; ++ct) {
      bf16x8 b[4];
#pragma unroll
      for (int ks = 0; ks < 4; ++ks)
        b[ks] = __builtin_bit_cast(
            bf16x8, *(const u32x4v*)(M + (ct * 16 + r16) * DD + ks * 32 + q * 8));
#pragma unroll
      for (int rt = 0; rt < 5; ++rt) {
        f32x4v acc = {0.f, 0.f, 0.f, 0.f};
#pragma unroll
        for (int ks = 0; ks < 4; ++ks) {
          bf16x8 a = __builtin_bit_cast(
              bf16x8, *(const u32x4v*)&kv_s[(rt * 16 + r16) * LSTR + ks * 32 + q * 8]);
          acc = __builtin_amdgcn_mfma_f32_16x16x32_bf16(a, b[ks], acc, 0, 0, 0);
        }
        int col = ct * 16 + r16;
#pragma unroll
        for (int r = 0; r < 4; ++r) {
          int row = rt * 16 + q * 4 + r;
          if (row < NROW) kvm_s[row * LSTR + col] = f2bf(acc[r]);
        }
      }
    }
  }
  __syncthreads();

  {
    int i = tid >> 2, sub = tid & 3;
    float s0 = 0.f, s1 = 0.f, s2 = 0.f;
#pragma unroll
    for (int ch = 0; ch < 4; ++ch) {
      int off = sub * 32 + ch * 8;
      float xf[8];
      {
        u32x4v t = *(const u32x4v*)&x_s[i * LSTR + off];
        xf[0] = BF_LO(t.x); xf[1] = BF_HI(t.x); xf[2] = BF_LO(t.y); xf[3] = BF_HI(t.y);
        xf[4] = BF_LO(t.z); xf[5] = BF_HI(t.z); xf[6] = BF_LO(t.w); xf[7] = BF_HI(t.w);
      }
      {
        u32x4v t = *(const u32x4v*)&kvm_s[(i + 0) * LSTR + off];
        s0 += xf[0]*BF_LO(t.x) + xf[1]*BF_HI(t.x) + xf[2]*BF_LO(t.y) + xf[3]*BF_HI(t.y)
            + xf[4]*BF_LO(t.z) + xf[5]*BF_HI(t.z) + xf[6]*BF_LO(t.w) + xf[7]*BF_HI(t.w);
      }
      {
        u32x4v t = *(const u32x4v*)&kvm_s[(i + 1) * LSTR + off];
        s1 += xf[0]*BF_LO(t.x) + xf[1]*BF_HI(t.x) + xf[2]*BF_LO(t.y) + xf[3]*BF_HI(t.y)
            + xf[4]*BF_LO(t.z) + xf[5]*BF_HI(t.z) + xf[6]*BF_LO(t.w) + xf[7]*BF_HI(t.w);
      }
      {
        u32x4v t = *(const u32x4v*)&kvm_s[(i + 2) * LSTR + off];
        s2 += xf[0]*BF_LO(t.x) + xf[1]*BF_HI(t.x) + xf[2]*BF_LO(t.y) + xf[3]*BF_HI(t.y)
            + xf[4]*BF_LO(t.z) + xf[5]*BF_HI(t.z) + xf[6]*BF_LO(t.w) + xf[7]*BF_HI(t.w);
      }
    }
    s0 += __shfl_xor(s0, 1); s0 += __shfl_xor(s0, 2);
    s1 += __shfl_xor(s1, 1); s1 += __shfl_xor(s1, 2);
    s2 += __shfl_xor(s2, 1); s2 += __shfl_xor(s2, 2);
    if (sub == 0) {
      int gp = seg0 + i;
      s_s[0 * TILE + i] = (gp - 1 >= 0)   ? s0 : -1e30f;
      s_s[1 * TILE + i] = s1;
      s_s[2 * TILE + i] = (gp + 1 < LINE) ? s2 : -1e30f;
    }
  }
  __syncthreads();

  if (tid < TILE) {
    float s0 = s_s[0 * TILE + tid], s1 = s_s[1 * TILE + tid], s2 = s_s[2 * TILE + tid];
    float m = fmaxf(s0, fmaxf(s1, s2));
    float e0 = __expf(s0 - m), e1 = __expf(s1 - m), e2 = __expf(s2 - m);
    float inv = 1.f / (e0 + e1 + e2);
    p_s[0 * TILE + tid] = e0 * inv;
    p_s[1 * TILE + tid] = e1 * inv;
    p_s[2 * TILE + tid] = e2 * inv;
  }
  __syncthreads();

  for (int r = 0; r < 16; ++r) {
    int u  = r * 256 + tid;
    int i  = u >> 6, dp = u & 63;
    float p0 = p_s[0 * TILE + i], p1 = p_s[1 * TILE + i], p2 = p_s[2 * TILE + i];
    unsigned a0 = *(const unsigned*)&kv_s[(i + 0) * LSTR + dp * 2];
    unsigned a1 = *(const unsigned*)&kv_s[(i + 1) * LSTR + dp * 2];
    unsigned a2 = *(const unsigned*)&kv_s[(i + 2) * LSTR + dp * 2];
    f32x2v o;
    o.x = p0 * BF_LO(a0) + p1 * BF_LO(a1) + p2 * BF_LO(a2);
    o.y = p0 * BF_HI(a0) + p1 * BF_HI(a1) + p2 * BF_HI(a2);
    size_t oidx = base + (size_t)(seg0 + i) * stride + dp * 2;
    if (ADD) {
      f32x2v prev = *(const f32x2v*)(out + oidx);
      o.x += prev.x; o.y += prev.y;
    }
    *(f32x2v*)(out + oidx) = o;
  }
}

// =====================================================================
extern "C" void kernel_launch(void* const* d_in, const int* in_sizes, int n_in,
                              void* d_out, int out_size, void* d_ws, size_t ws_size,
                              hipStream_t stream) {
  const float* x    = (const float*)d_in[0];
  const float* kv   = (const float*)d_in[1];
  const float* Wq_h = (const float*)d_in[2];
  const float* Wk_h = (const float*)d_in[3];
  const float* Wq_w = (const float*)d_in[4];
  const float* Wk_w = (const float*)d_in[5];
  float* out = (float*)d_out;

  const size_t ms_bytes = 2ull * DD * DD * 2;  // 65536

  if (ws_size >= ms_bytes) {
    unsigned short* Ms = (unsigned short*)d_ws;
    make_mt_kernel<<<dim3(DD, 2), dim3(DD), 0, stream>>>(Wq_h, Wk_h, Wq_w, Wk_w, Ms);
    fused_kernel<<<dim3(LINE / BP, 4 * LINE), dim3(256), 0, stream>>>(x, kv, Ms, out);
  } else {
    unsigned short* Ms = (unsigned short*)d_ws;  // 64 KB
    make_m_kernel<<<dim3(DD, 2), dim3(DD), 0, stream>>>(Wq_h, Wk_h, Wq_w, Wk_w, Ms);
    dim3 grid(LINE / TILE, 4 * 256);
    axial_pass<0, false><<<grid, dim3(256), 0, stream>>>(x, kv, Ms, out);
    axial_pass<1, true ><<<grid, dim3(256), 0, stream>>>(x, kv, Ms + DD * DD, out);
  }
}